// Round 9
// baseline (682.091 us; speedup 1.0000x reference)
//
#include <hip/hip_runtime.h>
#include <hip/hip_bf16.h>

#define NN   40000
#define NE   160000
#define ETOT 200000   // NE + NN self loops
#define FIN  602
#define NH1  8
#define C1   256
#define F1   2048     // NH1*C1
#define C2   42
#define NEG  0.2f
#define NB   157      // ceil(NN/256)
#define KP   608      // FIN padded to mult of 32
#define MP   40064    // NN padded to mult of 128 (313*128)
#define NWG1 5008     // 16 * 313 blocks for gemm1, 5008 = 8 XCD * 626

typedef unsigned short u16;
typedef unsigned int   u32;
typedef __bf16 bf16x8 __attribute__((ext_vector_type(8)));
typedef float  f32x4  __attribute__((ext_vector_type(4)));

__device__ __forceinline__ float bfu(u16 v){ return __uint_as_float(((u32)v) << 16); }
__device__ __forceinline__ float bflo(u32 u){ return __uint_as_float(u << 16); }
__device__ __forceinline__ float bfhi(u32 u){ return __uint_as_float(u & 0xffff0000u); }
__device__ __forceinline__ u16 f2bf(float f){
  u32 u = __float_as_uint(f);
  u32 r = (u + 0x7fffu + ((u >> 16) & 1u)) >> 16;   // RNE
  return (u16)r;
}

// ================= dtype probe =================
__global__ void probe_k(const u32* __restrict__ xw, const int* __restrict__ ei,
                        int* __restrict__ flags) {
  if (threadIdx.x == 0) {
    int zc = 0;
    for (int k = 0; k < 64; ++k) zc += (ei[2*k + 1] == 0) ? 1 : 0;
    flags[0] = (zc == 64) ? 1 : 0;
    int inr = 0;
    for (int k = 0; k < 64; ++k) {
      u32 low = xw[k] & 0xffffu;
      int e = (int)((low >> 7) & 0xff);
      inr += (e >= 100 && e <= 140) ? 1 : 0;
    }
    flags[1] = (inr >= 32) ? 0 : 1;
  }
}

__global__ void cvt_f32_k(const void* __restrict__ src, float* __restrict__ dst, int n,
                          const int* __restrict__ flags) {
  int i = blockIdx.x * 256 + threadIdx.x;
  if (i >= n) return;
  dst[i] = flags[1] ? ((const float*)src)[i] : bfu(((const u16*)src)[i]);
}

// xb[MP][KP] = x as bf16, zero-padded rows/cols
__global__ void xb_k(const void* __restrict__ x, u16* __restrict__ xb,
                     const int* __restrict__ flags) {
  int k = blockIdx.x * 256 + threadIdx.x;
  int row = blockIdx.y;
  if (k >= KP) return;
  u16 v = 0;
  if (row < NN && k < FIN)
    v = flags[1] ? f2bf(((const float*)x)[(size_t)row * FIN + k])
                 : ((const u16*)x)[(size_t)row * FIN + k];
  xb[(size_t)row * KP + k] = v;
}

// W1t[n][k] = W1[k][n], k padded to 608 with zeros. bf16.
__global__ void w1t_k(const void* __restrict__ W1, u16* __restrict__ w1t,
                      const int* __restrict__ flags) {
  int n = blockIdx.x * 256 + threadIdx.x;
  int k = blockIdx.y;
  if (n >= F1) return;
  u16 v = 0;
  if (k < FIN) v = flags[1] ? f2bf(((const float*)W1)[(size_t)k * F1 + n])
                            : ((const u16*)W1)[(size_t)k * F1 + n];
  w1t[(size_t)n * KP + k] = v;
}

// w2t[c][k] = W2[k][c], c padded 42->64 with zeros. bf16.
__global__ void w2t_k(const void* __restrict__ W2, u16* __restrict__ w2t,
                      const int* __restrict__ flags) {
  int i = blockIdx.x * 256 + threadIdx.x;
  if (i >= 64 * F1) return;
  int c = i >> 11, k = i & (F1 - 1);
  u16 v = 0;
  if (c < C2) v = flags[1] ? f2bf(((const float*)W2)[(size_t)k * C2 + c])
                           : ((const u16*)W2)[(size_t)k * C2 + c];
  w2t[i] = v;
}

// ================= CSR build =================
__device__ __forceinline__ void edge_sd(const int* __restrict__ ei, int e, int imode,
                                        int& s, int& d) {
  if (e < NE) {
    if (imode) { s = ei[2*e]; d = ei[2*(NE + e)]; }
    else       { s = ei[e];   d = ei[NE + e];     }
  } else { s = d = e - NE; }
}

__global__ void deg_k(const int* __restrict__ ei, int* __restrict__ deg,
                      const int* __restrict__ flags) {
  int e = blockIdx.x * 256 + threadIdx.x;
  if (e >= ETOT) return;
  int s, d; edge_sd(ei, e, flags[0], s, d);
  atomicAdd(&deg[d], 1);
}

__global__ __launch_bounds__(256) void scan1_k(const int* __restrict__ deg,
                                               int* __restrict__ tmp, int* __restrict__ bsum) {
  __shared__ int s[256];
  int b = blockIdx.x, t = threadIdx.x, i = b * 256 + t;
  int v = (i < NN) ? deg[i] : 0;
  s[t] = v; __syncthreads();
  for (int o = 1; o < 256; o <<= 1) {
    int u = (t >= o) ? s[t - o] : 0;
    __syncthreads(); s[t] += u; __syncthreads();
  }
  if (i < NN) tmp[i] = s[t];
  if (t == 255) bsum[b] = s[255];
}

__global__ __launch_bounds__(256) void scan2_k(int* __restrict__ bsum) {
  __shared__ int s[256];
  int t = threadIdx.x;
  int v = (t < NB) ? bsum[t] : 0;
  s[t] = v; __syncthreads();
  for (int o = 1; o < 256; o <<= 1) {
    int u = (t >= o) ? s[t - o] : 0;
    __syncthreads(); s[t] += u; __syncthreads();
  }
  if (t < NB) bsum[t] = s[t];
}

__global__ void scan3_k(const int* __restrict__ deg, const int* __restrict__ tmp,
                        const int* __restrict__ bsum, int* __restrict__ start, int* __restrict__ cur) {
  int i = blockIdx.x * 256 + threadIdx.x;
  if (i >= NN) return;
  int b = i >> 8;
  int off = b ? bsum[b - 1] : 0;
  int excl = tmp[i] - deg[i] + off;
  start[i] = excl; cur[i] = excl;
}

__global__ void fill_k(const int* __restrict__ ei, int* __restrict__ cur,
                       int* __restrict__ csr_src, int* __restrict__ csr_dst,
                       const int* __restrict__ flags) {
  int e = blockIdx.x * 256 + threadIdx.x;
  if (e >= ETOT) return;
  int s, d; edge_sd(ei, e, flags[0], s, d);
  int pos = atomicAdd(&cur[d], 1);
  csr_src[pos] = s; csr_dst[pos] = d;
}

// ================= GEMM1 path A: DIRECT-REGISTER MFMA + XCD-chunked swizzle
// 128x128 tile, 4 waves 2x2; fragments straight from global; each XCD owns a
// contiguous chunk of (row,col) tiles -> A-panels + whole w1t stay hot in its L2.
__global__ __launch_bounds__(256) void gemm1b_k(const u16* __restrict__ xb,
                                                const u16* __restrict__ w1t,
                                                u16* __restrict__ h1,
                                                const float* __restrict__ as1c,
                                                const float* __restrict__ ad1c,
                                                float* __restrict__ a_s1,
                                                float* __restrict__ a_d1) {
  const int t = threadIdx.x;
  const int lane = t & 63, wid = t >> 6;
  const int wr = wid >> 1, wc = wid & 1;
  // XCD swizzle: 5008 = 8 * 626; consecutive bids round-robin XCDs, so give
  // xcd = bid&7 the contiguous range [xcd*626, (xcd+1)*626) of tiles.
  const int bid = blockIdx.x;
  const int swz = (bid & 7) * (NWG1 / 8) + (bid >> 3);
  const int m0 = (swz >> 4) * 128;    // row tile (313)
  const int n0 = (swz & 15) * 128;    // col tile (16)
  const int l16 = lane & 15, lk = (lane >> 4) * 8;
  f32x4 acc[4][4];
  #pragma unroll
  for (int i = 0; i < 4; ++i)
    #pragma unroll
    for (int j = 0; j < 4; ++j) acc[i][j] = (f32x4){0.f, 0.f, 0.f, 0.f};

  const u16* Ap = xb  + (size_t)(m0 + wr * 64 + l16) * KP + lk;
  const u16* Bp = w1t + (size_t)(n0 + wc * 64 + l16) * KP + lk;

  bf16x8 a[4], b[4];
  #pragma unroll
  for (int i = 0; i < 4; ++i) {
    a[i] = *(const bf16x8*)(Ap + (size_t)i * 16 * KP);
    b[i] = *(const bf16x8*)(Bp + (size_t)i * 16 * KP);
  }
  for (int k0 = 32; k0 < KP; k0 += 32) {
    bf16x8 an[4], bn[4];
    #pragma unroll
    for (int i = 0; i < 4; ++i) {
      an[i] = *(const bf16x8*)(Ap + (size_t)i * 16 * KP + k0);
      bn[i] = *(const bf16x8*)(Bp + (size_t)i * 16 * KP + k0);
    }
    #pragma unroll
    for (int mi = 0; mi < 4; ++mi)
      #pragma unroll
      for (int ni = 0; ni < 4; ++ni)
        acc[mi][ni] = __builtin_amdgcn_mfma_f32_16x16x32_bf16(a[mi], b[ni], acc[mi][ni], 0, 0, 0);
    #pragma unroll
    for (int i = 0; i < 4; ++i) { a[i] = an[i]; b[i] = bn[i]; }
  }
  #pragma unroll
  for (int mi = 0; mi < 4; ++mi)
    #pragma unroll
    for (int ni = 0; ni < 4; ++ni)
      acc[mi][ni] = __builtin_amdgcn_mfma_f32_16x16x32_bf16(a[mi], b[ni], acc[mi][ni], 0, 0, 0);

  // ---- fused att1: per-row weighted col sums -> shfl reduce -> atomic partials
  const int h0 = n0 >> 8;
  float psrc[4][4], pdst[4][4];
  #pragma unroll
  for (int mi = 0; mi < 4; ++mi)
    #pragma unroll
    for (int r = 0; r < 4; ++r) { psrc[mi][r] = 0.f; pdst[mi][r] = 0.f; }
  #pragma unroll
  for (int ni = 0; ni < 4; ++ni) {
    int col = n0 + wc * 64 + ni * 16 + l16;
    float wsv = as1c[col], wdv = ad1c[col];
    #pragma unroll
    for (int mi = 0; mi < 4; ++mi)
      #pragma unroll
      for (int r = 0; r < 4; ++r) {
        float v = acc[mi][ni][r];
        psrc[mi][r] += v * wsv;
        pdst[mi][r] += v * wdv;
      }
  }
  #pragma unroll
  for (int o = 1; o < 16; o <<= 1) {
    #pragma unroll
    for (int mi = 0; mi < 4; ++mi)
      #pragma unroll
      for (int r = 0; r < 4; ++r) {
        psrc[mi][r] += __shfl_xor(psrc[mi][r], o, 64);
        pdst[mi][r] += __shfl_xor(pdst[mi][r], o, 64);
      }
  }
  const int lr4 = (lane >> 4) * 4;
  if (l16 == 0) {
    #pragma unroll
    for (int mi = 0; mi < 4; ++mi)
      #pragma unroll
      for (int r = 0; r < 4; ++r) {
        int row = m0 + wr * 64 + mi * 16 + lr4 + r;
        if (row < NN) {
          atomicAdd(&a_s1[row * NH1 + h0], psrc[mi][r]);
          atomicAdd(&a_d1[row * NH1 + h0], pdst[mi][r]);
        }
      }
  }

  // ---- h1 store
  #pragma unroll
  for (int mi = 0; mi < 4; ++mi) {
    #pragma unroll
    for (int r = 0; r < 4; ++r) {
      int row = m0 + wr * 64 + mi * 16 + lr4 + r;
      if (row < NN) {
        #pragma unroll
        for (int ni = 0; ni < 4; ++ni) {
          int col = n0 + wc * 64 + ni * 16 + l16;
          h1[(size_t)row * F1 + col] = f2bf(acc[mi][ni][r]);
        }
      }
    }
  }
}

// ================= GEMM1 path B (fallback, reg-staged, dual-dtype) =================
__global__ __launch_bounds__(256) void gemm1m_k(const void* __restrict__ xv,
                                                const u16* __restrict__ w1t,
                                                u16* __restrict__ h1,
                                                const int* __restrict__ flags) {
  __shared__ u16 As[128][40];
  __shared__ u16 Bs[128][40];
  const int fm = flags[1];
  const int t = threadIdx.x;
  const int lane = t & 63, wid = t >> 6;
  const int wr = wid >> 1, wc = wid & 1;
  const int m0 = blockIdx.y * 128, n0 = blockIdx.x * 128;
  const int l16 = lane & 15, lk = (lane >> 4) * 8;
  f32x4 acc[4][4];
  #pragma unroll
  for (int i = 0; i < 4; ++i)
    #pragma unroll
    for (int j = 0; j < 4; ++j) acc[i][j] = (f32x4){0.f, 0.f, 0.f, 0.f};
  const int arow = t >> 2;
  const int akb  = (t & 3) * 8;
  for (int k0 = 0; k0 < KP; k0 += 32) {
    #pragma unroll
    for (int i = 0; i < 2; ++i) {
      int row = arow + i * 64;
      int rg = m0 + row;
      u32 d0 = 0, d1 = 0, d2 = 0, d3 = 0;
      if (rg < NN) {
        if (k0 + 32 <= FIN) {
          if (fm) {
            const float* xp = (const float*)xv + (size_t)rg * FIN + k0 + akb;
            float2 p0 = *(const float2*)(xp);
            float2 p1 = *(const float2*)(xp + 2);
            float2 p2 = *(const float2*)(xp + 4);
            float2 p3 = *(const float2*)(xp + 6);
            d0 = (u32)f2bf(p0.x) | ((u32)f2bf(p0.y) << 16);
            d1 = (u32)f2bf(p1.x) | ((u32)f2bf(p1.y) << 16);
            d2 = (u32)f2bf(p2.x) | ((u32)f2bf(p2.y) << 16);
            d3 = (u32)f2bf(p3.x) | ((u32)f2bf(p3.y) << 16);
          } else {
            const u16* xp = (const u16*)xv + (size_t)rg * FIN + k0 + akb;
            d0 = *(const u32*)(xp);
            d1 = *(const u32*)(xp + 2);
            d2 = *(const u32*)(xp + 4);
            d3 = *(const u32*)(xp + 6);
          }
        } else {
          u16 e[8];
          #pragma unroll
          for (int q = 0; q < 8; ++q) {
            int k = k0 + akb + q;
            e[q] = 0;
            if (k < FIN)
              e[q] = fm ? f2bf(((const float*)xv)[(size_t)rg * FIN + k])
                        : ((const u16*)xv)[(size_t)rg * FIN + k];
          }
          d0 = (u32)e[0] | ((u32)e[1] << 16);
          d1 = (u32)e[2] | ((u32)e[3] << 16);
          d2 = (u32)e[4] | ((u32)e[5] << 16);
          d3 = (u32)e[6] | ((u32)e[7] << 16);
        }
      }
      *(uint4*)&As[row][akb] = make_uint4(d0, d1, d2, d3);
      const u16* wp = w1t + (size_t)(n0 + row) * KP + k0 + akb;
      *(uint4*)&Bs[row][akb] = *(const uint4*)wp;
    }
    __syncthreads();
    bf16x8 bfr[4];
    #pragma unroll
    for (int ni = 0; ni < 4; ++ni)
      bfr[ni] = *(const bf16x8*)&Bs[wc * 64 + ni * 16 + l16][lk];
    #pragma unroll
    for (int mi = 0; mi < 4; ++mi) {
      bf16x8 af = *(const bf16x8*)&As[wr * 64 + mi * 16 + l16][lk];
      #pragma unroll
      for (int ni = 0; ni < 4; ++ni)
        acc[mi][ni] = __builtin_amdgcn_mfma_f32_16x16x32_bf16(af, bfr[ni], acc[mi][ni], 0, 0, 0);
    }
    __syncthreads();
  }
  const int lr4 = (lane >> 4) * 4;
  #pragma unroll
  for (int mi = 0; mi < 4; ++mi) {
    #pragma unroll
    for (int r = 0; r < 4; ++r) {
      int row = m0 + wr * 64 + mi * 16 + lr4 + r;
      if (row < NN) {
        #pragma unroll
        for (int ni = 0; ni < 4; ++ni) {
          int col = n0 + wc * 64 + ni * 16 + l16;
          h1[(size_t)row * F1 + col] = f2bf(acc[mi][ni][r]);
        }
      }
    }
  }
}

// ================= attention scalars (fallback path only)
__global__ __launch_bounds__(256) void att1_k(const u16* __restrict__ h1,
                                              const float* __restrict__ as1c, const float* __restrict__ ad1c,
                                              float* __restrict__ a_s, float* __restrict__ a_d) {
  int n = blockIdx.x, t = threadIdx.x;
  int h = t >> 5, l = t & 31;
  int base = h * C1 + l * 8;
  const u16* hp = h1 + (size_t)n * F1 + base;
  uint4 v = *(const uint4*)hp;
  u32 w[4] = {v.x, v.y, v.z, v.w};
  float ss = 0.f, sd = 0.f;
  #pragma unroll
  for (int p = 0; p < 4; ++p) {
    float e0 = bflo(w[p]), e1 = bfhi(w[p]);
    ss += e0 * as1c[base + 2*p] + e1 * as1c[base + 2*p + 1];
    sd += e0 * ad1c[base + 2*p] + e1 * ad1c[base + 2*p + 1];
  }
  #pragma unroll
  for (int o = 16; o > 0; o >>= 1) {
    ss += __shfl_down(ss, o, 32);
    sd += __shfl_down(sd, o, 32);
  }
  if (l == 0) { a_s[n * NH1 + h] = ss; a_d[n * NH1 + h] = sd; }
}

// ================= fused: gather(vectorized)+bias+ReLU -> LDS -> MFMA @ w2t -> h2
// 512 threads: two 256-thread halves each gather 8 of the block's 16 nodes.
// Phase B: 8 waves = 4 col-groups x 2 K-halves, LDS partial reduce.
__global__ __launch_bounds__(512) void gfuse_k(const int* __restrict__ start, const int* __restrict__ deg,
                                               const int* __restrict__ csr_src,
                                               const float* __restrict__ a_s1, const float* __restrict__ a_d1,
                                               const u16* __restrict__ h1, const float* __restrict__ b1c,
                                               const u16* __restrict__ w2t, float* __restrict__ h2) {
  __shared__ u16 rowsL[16 * F1];   // 64 KB
  __shared__ float pb[4][16][16];  // 4 KB K-half partials
  int t = threadIdx.x;
  int nb = blockIdx.x * 16;
  int sub = t & 255, grp = t >> 8;
  int h = sub >> 5;
  int c0 = sub * 8;
  float4 bA = *(const float4*)(b1c + c0);
  float4 bB = *(const float4*)(b1c + c0 + 4);
  for (int ii = 0; ii < 8; ++ii) {
    int i = grp * 8 + ii;
    int n = nb + i;
    int s0 = start[n], jend = s0 + deg[n];
    float ad = a_d1[n * NH1 + h];
    float a0=0.f,a1=0.f,a2=0.f,a3=0.f,a4=0.f,a5=0.f,a6=0.f,a7=0.f,den=0.f;
    int j = s0;
    for (; j + 2 <= jend; j += 2) {
      int sA = csr_src[j], sB = csr_src[j + 1];
      float vA = a_s1[sA * NH1 + h] + ad;
      float vB = a_s1[sB * NH1 + h] + ad;
      vA = vA > 0.f ? vA : NEG * vA;
      vB = vB > 0.f ? vB : NEG * vB;
      float eA = expf(vA), eB = expf(vB);
      uint4 uA = *(const uint4*)(h1 + (size_t)sA * F1 + c0);
      uint4 uB = *(const uint4*)(h1 + (size_t)sB * F1 + c0);
      den += eA + eB;
      a0 += eA * bflo(uA.x) + eB * bflo(uB.x);
      a1 += eA * bfhi(uA.x) + eB * bfhi(uB.x);
      a2 += eA * bflo(uA.y) + eB * bflo(uB.y);
      a3 += eA * bfhi(uA.y) + eB * bfhi(uB.y);
      a4 += eA * bflo(uA.z) + eB * bflo(uB.z);
      a5 += eA * bfhi(uA.z) + eB * bfhi(uB.z);
      a6 += eA * bflo(uA.w) + eB * bflo(uB.w);
      a7 += eA * bfhi(uA.w) + eB * bfhi(uB.w);
    }
    if (j < jend) {
      int sA = csr_src[j];
      float vA = a_s1[sA * NH1 + h] + ad;
      vA = vA > 0.f ? vA : NEG * vA;
      float eA = expf(vA);
      uint4 uA = *(const uint4*)(h1 + (size_t)sA * F1 + c0);
      den += eA;
      a0 += eA * bflo(uA.x); a1 += eA * bfhi(uA.x);
      a2 += eA * bflo(uA.y); a3 += eA * bfhi(uA.y);
      a4 += eA * bflo(uA.z); a5 += eA * bfhi(uA.z);
      a6 += eA * bflo(uA.w); a7 += eA * bfhi(uA.w);
    }
    float inv = 1.f / (den + 1e-16f);
    u16 o0 = f2bf(fmaxf(a0 * inv + bA.x, 0.f));
    u16 o1 = f2bf(fmaxf(a1 * inv + bA.y, 0.f));
    u16 o2 = f2bf(fmaxf(a2 * inv + bA.z, 0.f));
    u16 o3 = f2bf(fmaxf(a3 * inv + bA.w, 0.f));
    u16 o4 = f2bf(fmaxf(a4 * inv + bB.x, 0.f));
    u16 o5 = f2bf(fmaxf(a5 * inv + bB.y, 0.f));
    u16 o6 = f2bf(fmaxf(a6 * inv + bB.z, 0.f));
    u16 o7 = f2bf(fmaxf(a7 * inv + bB.w, 0.f));
    uint4 pk;
    pk.x = (u32)o0 | ((u32)o1 << 16);
    pk.y = (u32)o2 | ((u32)o3 << 16);
    pk.z = (u32)o4 | ((u32)o5 << 16);
    pk.w = (u32)o6 | ((u32)o7 << 16);
    int sw = (i & 7) << 3;
    *(uint4*)&rowsL[i * F1 + (c0 ^ sw)] = pk;
  }
  __syncthreads();
  // phase B: C[16 nodes][64 cols] = rowsL @ w2t^T; wave = (col-group g, K-half kh)
  int lane = t & 63, wid = t >> 6;       // 8 waves
  int g = wid & 3, kh = wid >> 2;
  int l16 = lane & 15, lk = (lane >> 4) * 8;
  const u16* wt = w2t + (size_t)(g * 16 + l16) * F1;
  int sw = (l16 & 7) << 3;
  f32x4 acc2 = (f32x4){0.f, 0.f, 0.f, 0.f};
  const int kbase = kh * (F1 / 2);
  for (int k0 = 0; k0 < F1 / 2; k0 += 32) {
    int kk = kbase + k0 + lk;
    bf16x8 af = *(const bf16x8*)&rowsL[l16 * F1 + (kk ^ sw)];
    bf16x8 bf = *(const bf16x8*)(wt + kk);
    acc2 = __builtin_amdgcn_mfma_f32_16x16x32_bf16(af, bf, acc2, 0, 0, 0);
  }
  int mb = (lane >> 4) * 4;
  if (kh == 1) {
    #pragma unroll
    for (int r = 0; r < 4; ++r) pb[g][mb + r][l16] = acc2[r];
  }
  __syncthreads();
  if (kh == 0) {
    int col = g * 16 + l16;
    if (col < C2) {
      #pragma unroll
      for (int r = 0; r < 4; ++r)
        h2[(size_t)(nb + mb + r) * C2 + col] = acc2[r] + pb[g][mb + r][l16];
    }
  }
}

// ================= attention scalars layer 2
__global__ __launch_bounds__(64) void att2_k(const float* __restrict__ h2,
                                             const float* __restrict__ as2, const float* __restrict__ ad2,
                                             float* __restrict__ a_s, float* __restrict__ a_d) {
  int n = blockIdx.x, t = threadIdx.x;
  float ss = 0.f, sd = 0.f;
  if (t < C2) {
    float v = h2[(size_t)n * C2 + t];
    ss = v * as2[t];
    sd = v * ad2[t];
  }
  #pragma unroll
  for (int o = 32; o > 0; o >>= 1) {
    ss += __shfl_down(ss, o, 64);
    sd += __shfl_down(sd, o, 64);
  }
  if (t == 0) { a_s[n] = ss; a_d[n] = sd; }
}

// ================= layer-2 gather + bias + log_softmax, dual-format output
__global__ __launch_bounds__(64) void gath2_k(const int* __restrict__ start, const int* __restrict__ deg,
                                              const int* __restrict__ csr_src,
                                              const float* __restrict__ a_s, const float* __restrict__ a_d,
                                              const float* __restrict__ h2, const float* __restrict__ b2,
                                              void* __restrict__ outv, const int* __restrict__ flags) {
  int n = blockIdx.x, t = threadIdx.x;
  int s0 = start[n], cnt = deg[n];
  float ad = a_d[n];
  float acc = 0.f, den = 0.f;
  for (int j = s0; j < s0 + cnt; ++j) {
    int s = csr_src[j];
    float v = a_s[s] + ad;
    v = v > 0.f ? v : NEG * v;
    float e = expf(v);
    den += e;
    if (t < C2) acc += e * h2[(size_t)s * C2 + t];
  }
  float raw = (t < C2) ? acc / (den + 1e-16f) + b2[t] : -1e30f;
  float m = raw;
  #pragma unroll
  for (int o = 32; o > 0; o >>= 1) m = fmaxf(m, __shfl_down(m, o, 64));
  m = __shfl(m, 0, 64);
  float e2 = (t < C2) ? expf(raw - m) : 0.f;
  float ssum = e2;
  #pragma unroll
  for (int o = 32; o > 0; o >>= 1) ssum += __shfl_down(ssum, o, 64);
  ssum = __shfl(ssum, 0, 64);
  if (t < C2) {
    float v = raw - m - logf(ssum);
    if (flags[1]) ((float*)outv)[(size_t)n * C2 + t] = v;
    else          ((u16*) outv)[(size_t)n * C2 + t] = f2bf(v);
  }
}

extern "C" void kernel_launch(void* const* d_in, const int* in_sizes, int n_in,
                              void* d_out, int out_size, void* d_ws, size_t ws_size,
                              hipStream_t stream) {
  const void* x   = d_in[0];
  const int*  ei  = (const int*)d_in[1];
  const void* W1  = d_in[2];
  const void* as1 = d_in[3];
  const void* ad1 = d_in[4];
  const void* b1  = d_in[5];
  const void* W2  = d_in[6];
  const void* as2 = d_in[7];
  const void* ad2 = d_in[8];
  const void* b2  = d_in[9];

  char* ws = (char*)d_ws;
  u16*   h1      = (u16*)  (ws);                  // 163,840,000
  float* ex1     = (float*)(ws + 163840000);      //   6,400,000 (unused)
  float* h2      = (float*)(ws + 170240000);      //   6,720,000
  float* a_s1    = (float*)(ws + 176960000);      //   1,280,000
  float* a_d1    = (float*)(ws + 178240000);      //   1,280,000
  float* a_s2    = (float*)(ws + 179520000);      //     160,000
  float* a_d2    = (float*)(ws + 179680000);      //     160,000
  int*   deg     = (int*)  (ws + 179840000);      //     160,000
  int*   start   = (int*)  (ws + 180000000);      //     160,000
  int*   cur     = (int*)  (ws + 180160000);      //     160,000
  int*   tmp     = (int*)  (ws + 180320000);      //     160,000
  int*   csr_src = (int*)  (ws + 180480000);      //     800,000
  int*   csr_dst = (int*)  (ws + 181280000);      //     800,000
  int*   bsum    = (int*)  (ws + 182080000);      //       1,024
  u16*   w1t     = (u16*)  (ws + 182081024);      //   2,490,368
  u16*   w2t     = (u16*)  (ws + 184571392);      //     262,144
  float* as1c    = (float*)(ws + 184833536);      //       8,192
  float* ad1c    = (float*)(ws + 184841728);      //       8,192
  float* b1c     = (float*)(ws + 184849920);      //       8,192
  float* as2c    = (float*)(ws + 184858112);      //         256
  float* ad2c    = (float*)(ws + 184858368);      //         256
  float* b2c     = (float*)(ws + 184858624);      //         256
  int*   flags   = (int*)  (ws + 184858880);      //         256
  const size_t TOTAL_BASE = 184859136;
  u16*   xb      = (u16*)  (ws + TOTAL_BASE);     //  48,717,824 (path A only)
  const size_t TOTAL_A = TOTAL_BASE + (size_t)MP * KP * 2;  // 233,576,960
  if (ws_size < TOTAL_BASE) return;
  const bool pathA = (ws_size >= TOTAL_A);
  (void)ex1;

  probe_k<<<1, 64, 0, stream>>>((const u32*)x, ei, flags);

  cvt_f32_k<<<(F1 + 255) / 256, 256, 0, stream>>>(as1, as1c, F1, flags);
  cvt_f32_k<<<(F1 + 255) / 256, 256, 0, stream>>>(ad1, ad1c, F1, flags);
  cvt_f32_k<<<(F1 + 255) / 256, 256, 0, stream>>>(b1, b1c, F1, flags);
  cvt_f32_k<<<1, 256, 0, stream>>>(as2, as2c, C2, flags);
  cvt_f32_k<<<1, 256, 0, stream>>>(ad2, ad2c, C2, flags);
  cvt_f32_k<<<1, 256, 0, stream>>>(b2, b2c, C2, flags);
  w1t_k<<<dim3(8, KP), 256, 0, stream>>>(W1, w1t, flags);
  w2t_k<<<(64 * F1 + 255) / 256, 256, 0, stream>>>(W2, w2t, flags);

  hipMemsetAsync(deg, 0, NN * sizeof(int), stream);
  hipMemsetAsync(a_s1, 0, 2 * NN * NH1 * sizeof(float), stream);  // a_s1 + a_d1 contiguous
  const int EB = (ETOT + 255) / 256;
  deg_k  <<<EB, 256, 0, stream>>>(ei, deg, flags);
  scan1_k<<<NB, 256, 0, stream>>>(deg, tmp, bsum);
  scan2_k<<<1, 256, 0, stream>>>(bsum);
  scan3_k<<<NB, 256, 0, stream>>>(deg, tmp, bsum, start, cur);
  fill_k <<<EB, 256, 0, stream>>>(ei, cur, csr_src, csr_dst, flags);

  if (pathA) {
    xb_k<<<dim3((KP + 255) / 256, MP), 256, 0, stream>>>(x, xb, flags);
    gemm1b_k<<<NWG1, 256, 0, stream>>>(xb, w1t, h1, as1c, ad1c, a_s1, a_d1);
  } else {
    gemm1m_k<<<dim3(16, MP / 128), 256, 0, stream>>>(x, w1t, h1, flags);
    att1_k<<<NN, 256, 0, stream>>>(h1, as1c, ad1c, a_s1, a_d1);
  }
  gfuse_k<<<NN / 16, 512, 0, stream>>>(start, deg, csr_src, a_s1, a_d1, h1, b1c, w2t, h2);

  att2_k<<<NN, 64, 0, stream>>>(h2, as2c, ad2c, a_s2, a_d2);
  gath2_k<<<NN, 64, 0, stream>>>(start, deg, csr_src, a_s2, a_d2, h2, b2c, d_out, flags);
}

// Round 10
// 641.723 us; speedup vs baseline: 1.0629x; 1.0629x over previous
//
#include <hip/hip_runtime.h>
#include <hip/hip_bf16.h>

#define NN   40000
#define NE   160000
#define ETOT 200000   // NE + NN self loops
#define FIN  602
#define NH1  8
#define C1   256
#define F1   2048     // NH1*C1
#define C2   42
#define NEG  0.2f
#define NB   157      // ceil(NN/256)
#define KP   608      // FIN padded to mult of 32
#define MP   40192    // NN padded to mult of 256 (157*256)

typedef unsigned short u16;
typedef unsigned int   u32;
typedef __bf16 bf16x8 __attribute__((ext_vector_type(8)));
typedef float  f32x4  __attribute__((ext_vector_type(4)));

__device__ __forceinline__ float bfu(u16 v){ return __uint_as_float(((u32)v) << 16); }
__device__ __forceinline__ float bflo(u32 u){ return __uint_as_float(u << 16); }
__device__ __forceinline__ float bfhi(u32 u){ return __uint_as_float(u & 0xffff0000u); }
__device__ __forceinline__ u16 f2bf(float f){
  u32 u = __float_as_uint(f);
  u32 r = (u + 0x7fffu + ((u >> 16) & 1u)) >> 16;   // RNE
  return (u16)r;
}

// async global->LDS, 16B per lane; LDS dest = wave-uniform base + lane*16
__device__ __forceinline__ void gl_lds16(const u16* g, u16* l) {
  __builtin_amdgcn_global_load_lds(
      (const __attribute__((address_space(1))) u32*)(g),
      (__attribute__((address_space(3))) u32*)(l), 16, 0, 0);
}

// ================= dtype probe =================
__global__ void probe_k(const u32* __restrict__ xw, const int* __restrict__ ei,
                        int* __restrict__ flags) {
  if (threadIdx.x == 0) {
    int zc = 0;
    for (int k = 0; k < 64; ++k) zc += (ei[2*k + 1] == 0) ? 1 : 0;
    flags[0] = (zc == 64) ? 1 : 0;
    int inr = 0;
    for (int k = 0; k < 64; ++k) {
      u32 low = xw[k] & 0xffffu;
      int e = (int)((low >> 7) & 0xff);
      inr += (e >= 100 && e <= 140) ? 1 : 0;
    }
    flags[1] = (inr >= 32) ? 0 : 1;
  }
}

__global__ void cvt_f32_k(const void* __restrict__ src, float* __restrict__ dst, int n,
                          const int* __restrict__ flags) {
  int i = blockIdx.x * 256 + threadIdx.x;
  if (i >= n) return;
  dst[i] = flags[1] ? ((const float*)src)[i] : bfu(((const u16*)src)[i]);
}

// xb[MP][KP] = x as bf16, zero-padded rows/cols
__global__ void xb_k(const void* __restrict__ x, u16* __restrict__ xb,
                     const int* __restrict__ flags) {
  int k = blockIdx.x * 256 + threadIdx.x;
  int row = blockIdx.y;
  if (k >= KP) return;
  u16 v = 0;
  if (row < NN && k < FIN)
    v = flags[1] ? f2bf(((const float*)x)[(size_t)row * FIN + k])
                 : ((const u16*)x)[(size_t)row * FIN + k];
  xb[(size_t)row * KP + k] = v;
}

// W1t[n][k] = W1[k][n], k padded to 608 with zeros. bf16.
__global__ void w1t_k(const void* __restrict__ W1, u16* __restrict__ w1t,
                      const int* __restrict__ flags) {
  int n = blockIdx.x * 256 + threadIdx.x;
  int k = blockIdx.y;
  if (n >= F1) return;
  u16 v = 0;
  if (k < FIN) v = flags[1] ? f2bf(((const float*)W1)[(size_t)k * F1 + n])
                            : ((const u16*)W1)[(size_t)k * F1 + n];
  w1t[(size_t)n * KP + k] = v;
}

// w2t[c][k] = W2[k][c], c padded 42->64 with zeros. bf16.
__global__ void w2t_k(const void* __restrict__ W2, u16* __restrict__ w2t,
                      const int* __restrict__ flags) {
  int i = blockIdx.x * 256 + threadIdx.x;
  if (i >= 64 * F1) return;
  int c = i >> 11, k = i & (F1 - 1);
  u16 v = 0;
  if (c < C2) v = flags[1] ? f2bf(((const float*)W2)[(size_t)k * C2 + c])
                           : ((const u16*)W2)[(size_t)k * C2 + c];
  w2t[i] = v;
}

// ================= CSR build =================
__device__ __forceinline__ void edge_sd(const int* __restrict__ ei, int e, int imode,
                                        int& s, int& d) {
  if (e < NE) {
    if (imode) { s = ei[2*e]; d = ei[2*(NE + e)]; }
    else       { s = ei[e];   d = ei[NE + e];     }
  } else { s = d = e - NE; }
}

__global__ void deg_k(const int* __restrict__ ei, int* __restrict__ deg,
                      const int* __restrict__ flags) {
  int e = blockIdx.x * 256 + threadIdx.x;
  if (e >= ETOT) return;
  int s, d; edge_sd(ei, e, flags[0], s, d);
  atomicAdd(&deg[d], 1);
}

__global__ __launch_bounds__(256) void scan1_k(const int* __restrict__ deg,
                                               int* __restrict__ tmp, int* __restrict__ bsum) {
  __shared__ int s[256];
  int b = blockIdx.x, t = threadIdx.x, i = b * 256 + t;
  int v = (i < NN) ? deg[i] : 0;
  s[t] = v; __syncthreads();
  for (int o = 1; o < 256; o <<= 1) {
    int u = (t >= o) ? s[t - o] : 0;
    __syncthreads(); s[t] += u; __syncthreads();
  }
  if (i < NN) tmp[i] = s[t];
  if (t == 255) bsum[b] = s[255];
}

__global__ __launch_bounds__(256) void scan2_k(int* __restrict__ bsum) {
  __shared__ int s[256];
  int t = threadIdx.x;
  int v = (t < NB) ? bsum[t] : 0;
  s[t] = v; __syncthreads();
  for (int o = 1; o < 256; o <<= 1) {
    int u = (t >= o) ? s[t - o] : 0;
    __syncthreads(); s[t] += u; __syncthreads();
  }
  if (t < NB) bsum[t] = s[t];
}

__global__ void scan3_k(const int* __restrict__ deg, const int* __restrict__ tmp,
                        const int* __restrict__ bsum, int* __restrict__ start, int* __restrict__ cur) {
  int i = blockIdx.x * 256 + threadIdx.x;
  if (i >= NN) return;
  int b = i >> 8;
  int off = b ? bsum[b - 1] : 0;
  int excl = tmp[i] - deg[i] + off;
  start[i] = excl; cur[i] = excl;
}

__global__ void fill_k(const int* __restrict__ ei, int* __restrict__ cur,
                       int* __restrict__ csr_src, int* __restrict__ csr_dst,
                       const int* __restrict__ flags) {
  int e = blockIdx.x * 256 + threadIdx.x;
  if (e >= ETOT) return;
  int s, d; edge_sd(ei, e, flags[0], s, d);
  int pos = atomicAdd(&cur[d], 1);
  csr_src[pos] = s; csr_dst[pos] = d;
}

// ================= GEMM1 path A: 256x256 tile, BK=32, 8 waves (2x4),
// double-buffered global_load_lds, chunk-XOR swizzle (round-7 verified),
// fused att1 partials. Each block covers exactly one head (N-tile = C1).
__global__ __launch_bounds__(512) void gemm1c_k(const u16* __restrict__ xb,
                                                const u16* __restrict__ w1t,
                                                u16* __restrict__ h1,
                                                const float* __restrict__ as1c,
                                                const float* __restrict__ ad1c,
                                                float* __restrict__ a_s1,
                                                float* __restrict__ a_d1) {
  __shared__ u16 As[2 * 8192];   // [buf][256 rows][32 k] = 32 KB
  __shared__ u16 Bs[2 * 8192];
  const int t = threadIdx.x;
  const int lane = t & 63, wid = t >> 6;   // 8 waves
  const int wr = wid >> 2, wc = wid & 3;   // 2 x 4 wave grid, wave tile 128x64
  const int m0 = blockIdx.y * 256, n0 = blockIdx.x * 256;
  const int l16 = lane & 15;
  f32x4 acc[8][4];
  #pragma unroll
  for (int i = 0; i < 8; ++i)
    #pragma unroll
    for (int j = 0; j < 4; ++j) acc[i][j] = (f32x4){0.f, 0.f, 0.f, 0.f};

  // staging: thread t -> LDS slot (row = t>>2 in 0..127 [+128 on 2nd issue], chunk = t&3)
  // source chunk inverse-swizzled: kc = (chunk ^ ((row>>1)&3)) * 8 elems
  const int kc = ((t & 3) ^ ((t >> 3) & 3)) * 8;
  const size_t sa0 = (size_t)(m0 + (t >> 2)) * KP + kc;
  const size_t sa1 = sa0 + (size_t)128 * KP;
  const size_t sb0 = (size_t)(n0 + (t >> 2)) * KP + kc;
  const size_t sb1 = sb0 + (size_t)128 * KP;

  // read swizzle: chunk(lane>>4) ^ ((row>>1)&3); frag row base mult of 16 -> (l16>>1)&3
  const int fsw = ((lane >> 4) ^ ((l16 >> 1) & 3)) << 3;
  const int rdA = (wr * 128 + l16) * 32 + fsw;   // + mi*512
  const int rdB = (wc * 64 + l16) * 32 + fsw;    // + ni*512

#define STAGE(K0, B) do {                                  \
    u16* a_ = As + (B) * 8192 + (wid << 9);                \
    u16* b_ = Bs + (B) * 8192 + (wid << 9);                \
    gl_lds16(xb  + sa0 + (K0), a_);                        \
    gl_lds16(xb  + sa1 + (K0), a_ + 4096);                 \
    gl_lds16(w1t + sb0 + (K0), b_);                        \
    gl_lds16(w1t + sb1 + (K0), b_ + 4096);                 \
  } while (0)

  STAGE(0, 0);
  __syncthreads();
  int cur = 0;
  for (int k0 = 0; k0 < KP; k0 += 32) {
    if (k0 + 32 < KP) STAGE(k0 + 32, cur ^ 1);   // prefetch next K-tile
    const u16* Ab = As + cur * 8192;
    const u16* Bb = Bs + cur * 8192;
    bf16x8 bfr[4];
    #pragma unroll
    for (int ni = 0; ni < 4; ++ni)
      bfr[ni] = *(const bf16x8*)&Bb[rdB + ni * 512];
    #pragma unroll
    for (int mi = 0; mi < 8; ++mi) {
      bf16x8 af = *(const bf16x8*)&Ab[rdA + mi * 512];
      #pragma unroll
      for (int ni = 0; ni < 4; ++ni)
        acc[mi][ni] = __builtin_amdgcn_mfma_f32_16x16x32_bf16(af, bfr[ni], acc[mi][ni], 0, 0, 0);
    }
    __syncthreads();   // next stage landed; cur reads done
    cur ^= 1;
  }
#undef STAGE

  // ---- epilogue per mi: fused att1 partials + h1 store (keeps VGPR bounded)
  const int h0 = n0 >> 8;          // head of this col tile (N-tile == C1)
  const int lr4 = (lane >> 4) * 4;
  #pragma unroll
  for (int mi = 0; mi < 8; ++mi) {
    float ps[4] = {0.f, 0.f, 0.f, 0.f}, pd[4] = {0.f, 0.f, 0.f, 0.f};
    #pragma unroll
    for (int ni = 0; ni < 4; ++ni) {
      int col = n0 + wc * 64 + ni * 16 + l16;
      float wsv = as1c[col], wdv = ad1c[col];
      #pragma unroll
      for (int r = 0; r < 4; ++r) {
        float v = acc[mi][ni][r];
        ps[r] += v * wsv;
        pd[r] += v * wdv;
      }
    }
    #pragma unroll
    for (int o = 1; o < 16; o <<= 1) {
      #pragma unroll
      for (int r = 0; r < 4; ++r) {
        ps[r] += __shfl_xor(ps[r], o, 64);
        pd[r] += __shfl_xor(pd[r], o, 64);
      }
    }
    int rowb = m0 + wr * 128 + mi * 16 + lr4;
    if (l16 == 0) {
      #pragma unroll
      for (int r = 0; r < 4; ++r) {
        int row = rowb + r;
        if (row < NN) {
          atomicAdd(&a_s1[row * NH1 + h0], ps[r]);
          atomicAdd(&a_d1[row * NH1 + h0], pd[r]);
        }
      }
    }
    #pragma unroll
    for (int r = 0; r < 4; ++r) {
      int row = rowb + r;
      if (row < NN) {
        #pragma unroll
        for (int ni = 0; ni < 4; ++ni) {
          int col = n0 + wc * 64 + ni * 16 + l16;
          h1[(size_t)row * F1 + col] = f2bf(acc[mi][ni][r]);
        }
      }
    }
  }
}

// ================= GEMM1 path B (fallback, reg-staged, dual-dtype) =================
__global__ __launch_bounds__(256) void gemm1m_k(const void* __restrict__ xv,
                                                const u16* __restrict__ w1t,
                                                u16* __restrict__ h1,
                                                const int* __restrict__ flags) {
  __shared__ u16 As[128][40];
  __shared__ u16 Bs[128][40];
  const int fm = flags[1];
  const int t = threadIdx.x;
  const int lane = t & 63, wid = t >> 6;
  const int wr = wid >> 1, wc = wid & 1;
  const int m0 = blockIdx.y * 128, n0 = blockIdx.x * 128;
  const int l16 = lane & 15, lk = (lane >> 4) * 8;
  f32x4 acc[4][4];
  #pragma unroll
  for (int i = 0; i < 4; ++i)
    #pragma unroll
    for (int j = 0; j < 4; ++j) acc[i][j] = (f32x4){0.f, 0.f, 0.f, 0.f};
  const int arow = t >> 2;
  const int akb  = (t & 3) * 8;
  for (int k0 = 0; k0 < KP; k0 += 32) {
    #pragma unroll
    for (int i = 0; i < 2; ++i) {
      int row = arow + i * 64;
      int rg = m0 + row;
      u32 d0 = 0, d1 = 0, d2 = 0, d3 = 0;
      if (rg < NN) {
        if (k0 + 32 <= FIN) {
          if (fm) {
            const float* xp = (const float*)xv + (size_t)rg * FIN + k0 + akb;
            float2 p0 = *(const float2*)(xp);
            float2 p1 = *(const float2*)(xp + 2);
            float2 p2 = *(const float2*)(xp + 4);
            float2 p3 = *(const float2*)(xp + 6);
            d0 = (u32)f2bf(p0.x) | ((u32)f2bf(p0.y) << 16);
            d1 = (u32)f2bf(p1.x) | ((u32)f2bf(p1.y) << 16);
            d2 = (u32)f2bf(p2.x) | ((u32)f2bf(p2.y) << 16);
            d3 = (u32)f2bf(p3.x) | ((u32)f2bf(p3.y) << 16);
          } else {
            const u16* xp = (const u16*)xv + (size_t)rg * FIN + k0 + akb;
            d0 = *(const u32*)(xp);
            d1 = *(const u32*)(xp + 2);
            d2 = *(const u32*)(xp + 4);
            d3 = *(const u32*)(xp + 6);
          }
        } else {
          u16 e[8];
          #pragma unroll
          for (int q = 0; q < 8; ++q) {
            int k = k0 + akb + q;
            e[q] = 0;
            if (k < FIN)
              e[q] = fm ? f2bf(((const float*)xv)[(size_t)rg * FIN + k])
                        : ((const u16*)xv)[(size_t)rg * FIN + k];
          }
          d0 = (u32)e[0] | ((u32)e[1] << 16);
          d1 = (u32)e[2] | ((u32)e[3] << 16);
          d2 = (u32)e[4] | ((u32)e[5] << 16);
          d3 = (u32)e[6] | ((u32)e[7] << 16);
        }
      }
      *(uint4*)&As[row][akb] = make_uint4(d0, d1, d2, d3);
      const u16* wp = w1t + (size_t)(n0 + row) * KP + k0 + akb;
      *(uint4*)&Bs[row][akb] = *(const uint4*)wp;
    }
    __syncthreads();
    bf16x8 bfr[4];
    #pragma unroll
    for (int ni = 0; ni < 4; ++ni)
      bfr[ni] = *(const bf16x8*)&Bs[wc * 64 + ni * 16 + l16][lk];
    #pragma unroll
    for (int mi = 0; mi < 4; ++mi) {
      bf16x8 af = *(const bf16x8*)&As[wr * 64 + mi * 16 + l16][lk];
      #pragma unroll
      for (int ni = 0; ni < 4; ++ni)
        acc[mi][ni] = __builtin_amdgcn_mfma_f32_16x16x32_bf16(af, bfr[ni], acc[mi][ni], 0, 0, 0);
    }
    __syncthreads();
  }
  const int lr4 = (lane >> 4) * 4;
  #pragma unroll
  for (int mi = 0; mi < 4; ++mi) {
    #pragma unroll
    for (int r = 0; r < 4; ++r) {
      int row = m0 + wr * 64 + mi * 16 + lr4 + r;
      if (row < NN) {
        #pragma unroll
        for (int ni = 0; ni < 4; ++ni) {
          int col = n0 + wc * 64 + ni * 16 + l16;
          h1[(size_t)row * F1 + col] = f2bf(acc[mi][ni][r]);
        }
      }
    }
  }
}

// ================= attention scalars (fallback path only)
__global__ __launch_bounds__(256) void att1_k(const u16* __restrict__ h1,
                                              const float* __restrict__ as1c, const float* __restrict__ ad1c,
                                              float* __restrict__ a_s, float* __restrict__ a_d) {
  int n = blockIdx.x, t = threadIdx.x;
  int h = t >> 5, l = t & 31;
  int base = h * C1 + l * 8;
  const u16* hp = h1 + (size_t)n * F1 + base;
  uint4 v = *(const uint4*)hp;
  u32 w[4] = {v.x, v.y, v.z, v.w};
  float ss = 0.f, sd = 0.f;
  #pragma unroll
  for (int p = 0; p < 4; ++p) {
    float e0 = bflo(w[p]), e1 = bfhi(w[p]);
    ss += e0 * as1c[base + 2*p] + e1 * as1c[base + 2*p + 1];
    sd += e0 * ad1c[base + 2*p] + e1 * ad1c[base + 2*p + 1];
  }
  #pragma unroll
  for (int o = 16; o > 0; o >>= 1) {
    ss += __shfl_down(ss, o, 32);
    sd += __shfl_down(sd, o, 32);
  }
  if (l == 0) { a_s[n * NH1 + h] = ss; a_d[n * NH1 + h] = sd; }
}

// ================= fused: gather(vectorized)+bias+ReLU -> LDS -> MFMA @ w2t -> h2
// 512 threads: two 256-thread halves each gather 8 of the block's 16 nodes.
// Phase B: 8 waves = 4 col-groups x 2 K-halves, LDS partial reduce.
__global__ __launch_bounds__(512) void gfuse_k(const int* __restrict__ start, const int* __restrict__ deg,
                                               const int* __restrict__ csr_src,
                                               const float* __restrict__ a_s1, const float* __restrict__ a_d1,
                                               const u16* __restrict__ h1, const float* __restrict__ b1c,
                                               const u16* __restrict__ w2t, float* __restrict__ h2) {
  __shared__ u16 rowsL[16 * F1];   // 64 KB
  __shared__ float pb[4][16][16];  // 4 KB K-half partials
  int t = threadIdx.x;
  int nb = blockIdx.x * 16;
  int sub = t & 255, grp = t >> 8;
  int h = sub >> 5;
  int c0 = sub * 8;
  float4 bA = *(const float4*)(b1c + c0);
  float4 bB = *(const float4*)(b1c + c0 + 4);
  for (int ii = 0; ii < 8; ++ii) {
    int i = grp * 8 + ii;
    int n = nb + i;
    int s0 = start[n], jend = s0 + deg[n];
    float ad = a_d1[n * NH1 + h];
    float a0=0.f,a1=0.f,a2=0.f,a3=0.f,a4=0.f,a5=0.f,a6=0.f,a7=0.f,den=0.f;
    int j = s0;
    for (; j + 2 <= jend; j += 2) {
      int sA = csr_src[j], sB = csr_src[j + 1];
      float vA = a_s1[sA * NH1 + h] + ad;
      float vB = a_s1[sB * NH1 + h] + ad;
      vA = vA > 0.f ? vA : NEG * vA;
      vB = vB > 0.f ? vB : NEG * vB;
      float eA = expf(vA), eB = expf(vB);
      uint4 uA = *(const uint4*)(h1 + (size_t)sA * F1 + c0);
      uint4 uB = *(const uint4*)(h1 + (size_t)sB * F1 + c0);
      den += eA + eB;
      a0 += eA * bflo(uA.x) + eB * bflo(uB.x);
      a1 += eA * bfhi(uA.x) + eB * bfhi(uB.x);
      a2 += eA * bflo(uA.y) + eB * bflo(uB.y);
      a3 += eA * bfhi(uA.y) + eB * bfhi(uB.y);
      a4 += eA * bflo(uA.z) + eB * bflo(uB.z);
      a5 += eA * bfhi(uA.z) + eB * bfhi(uB.z);
      a6 += eA * bflo(uA.w) + eB * bflo(uB.w);
      a7 += eA * bfhi(uA.w) + eB * bfhi(uB.w);
    }
    if (j < jend) {
      int sA = csr_src[j];
      float vA = a_s1[sA * NH1 + h] + ad;
      vA = vA > 0.f ? vA : NEG * vA;
      float eA = expf(vA);
      uint4 uA = *(const uint4*)(h1 + (size_t)sA * F1 + c0);
      den += eA;
      a0 += eA * bflo(uA.x); a1 += eA * bfhi(uA.x);
      a2 += eA * bflo(uA.y); a3 += eA * bfhi(uA.y);
      a4 += eA * bflo(uA.z); a5 += eA * bfhi(uA.z);
      a6 += eA * bflo(uA.w); a7 += eA * bfhi(uA.w);
    }
    float inv = 1.f / (den + 1e-16f);
    u16 o0 = f2bf(fmaxf(a0 * inv + bA.x, 0.f));
    u16 o1 = f2bf(fmaxf(a1 * inv + bA.y, 0.f));
    u16 o2 = f2bf(fmaxf(a2 * inv + bA.z, 0.f));
    u16 o3 = f2bf(fmaxf(a3 * inv + bA.w, 0.f));
    u16 o4 = f2bf(fmaxf(a4 * inv + bB.x, 0.f));
    u16 o5 = f2bf(fmaxf(a5 * inv + bB.y, 0.f));
    u16 o6 = f2bf(fmaxf(a6 * inv + bB.z, 0.f));
    u16 o7 = f2bf(fmaxf(a7 * inv + bB.w, 0.f));
    uint4 pk;
    pk.x = (u32)o0 | ((u32)o1 << 16);
    pk.y = (u32)o2 | ((u32)o3 << 16);
    pk.z = (u32)o4 | ((u32)o5 << 16);
    pk.w = (u32)o6 | ((u32)o7 << 16);
    int sw = (i & 7) << 3;
    *(uint4*)&rowsL[i * F1 + (c0 ^ sw)] = pk;
  }
  __syncthreads();
  // phase B: C[16 nodes][64 cols] = rowsL @ w2t^T; wave = (col-group g, K-half kh)
  int lane = t & 63, wid = t >> 6;       // 8 waves
  int g = wid & 3, kh = wid >> 2;
  int l16 = lane & 15, lk = (lane >> 4) * 8;
  const u16* wt = w2t + (size_t)(g * 16 + l16) * F1;
  int sw = (l16 & 7) << 3;
  f32x4 acc2 = (f32x4){0.f, 0.f, 0.f, 0.f};
  const int kbase = kh * (F1 / 2);
  for (int k0 = 0; k0 < F1 / 2; k0 += 32) {
    int kk = kbase + k0 + lk;
    bf16x8 af = *(const bf16x8*)&rowsL[l16 * F1 + (kk ^ sw)];
    bf16x8 bf = *(const bf16x8*)(wt + kk);
    acc2 = __builtin_amdgcn_mfma_f32_16x16x32_bf16(af, bf, acc2, 0, 0, 0);
  }
  int mb = (lane >> 4) * 4;
  if (kh == 1) {
    #pragma unroll
    for (int r = 0; r < 4; ++r) pb[g][mb + r][l16] = acc2[r];
  }
  __syncthreads();
  if (kh == 0) {
    int col = g * 16 + l16;
    if (col < C2) {
      #pragma unroll
      for (int r = 0; r < 4; ++r)
        h2[(size_t)(nb + mb + r) * C2 + col] = acc2[r] + pb[g][mb + r][l16];
    }
  }
}

// ================= attention scalars layer 2
__global__ __launch_bounds__(64) void att2_k(const float* __restrict__ h2,
                                             const float* __restrict__ as2, const float* __restrict__ ad2,
                                             float* __restrict__ a_s, float* __restrict__ a_d) {
  int n = blockIdx.x, t = threadIdx.x;
  float ss = 0.f, sd = 0.f;
  if (t < C2) {
    float v = h2[(size_t)n * C2 + t];
    ss = v * as2[t];
    sd = v * ad2[t];
  }
  #pragma unroll
  for (int o = 32; o > 0; o >>= 1) {
    ss += __shfl_down(ss, o, 64);
    sd += __shfl_down(sd, o, 64);
  }
  if (t == 0) { a_s[n] = ss; a_d[n] = sd; }
}

// ================= layer-2 gather + bias + log_softmax, dual-format output
__global__ __launch_bounds__(64) void gath2_k(const int* __restrict__ start, const int* __restrict__ deg,
                                              const int* __restrict__ csr_src,
                                              const float* __restrict__ a_s, const float* __restrict__ a_d,
                                              const float* __restrict__ h2, const float* __restrict__ b2,
                                              void* __restrict__ outv, const int* __restrict__ flags) {
  int n = blockIdx.x, t = threadIdx.x;
  int s0 = start[n], cnt = deg[n];
  float ad = a_d[n];
  float acc = 0.f, den = 0.f;
  for (int j = s0; j < s0 + cnt; ++j) {
    int s = csr_src[j];
    float v = a_s[s] + ad;
    v = v > 0.f ? v : NEG * v;
    float e = expf(v);
    den += e;
    if (t < C2) acc += e * h2[(size_t)s * C2 + t];
  }
  float raw = (t < C2) ? acc / (den + 1e-16f) + b2[t] : -1e30f;
  float m = raw;
  #pragma unroll
  for (int o = 32; o > 0; o >>= 1) m = fmaxf(m, __shfl_down(m, o, 64));
  m = __shfl(m, 0, 64);
  float e2 = (t < C2) ? expf(raw - m) : 0.f;
  float ssum = e2;
  #pragma unroll
  for (int o = 32; o > 0; o >>= 1) ssum += __shfl_down(ssum, o, 64);
  ssum = __shfl(ssum, 0, 64);
  if (t < C2) {
    float v = raw - m - logf(ssum);
    if (flags[1]) ((float*)outv)[(size_t)n * C2 + t] = v;
    else          ((u16*) outv)[(size_t)n * C2 + t] = f2bf(v);
  }
}

extern "C" void kernel_launch(void* const* d_in, const int* in_sizes, int n_in,
                              void* d_out, int out_size, void* d_ws, size_t ws_size,
                              hipStream_t stream) {
  const void* x   = d_in[0];
  const int*  ei  = (const int*)d_in[1];
  const void* W1  = d_in[2];
  const void* as1 = d_in[3];
  const void* ad1 = d_in[4];
  const void* b1  = d_in[5];
  const void* W2  = d_in[6];
  const void* as2 = d_in[7];
  const void* ad2 = d_in[8];
  const void* b2  = d_in[9];

  char* ws = (char*)d_ws;
  u16*   h1      = (u16*)  (ws);                  // 163,840,000
  float* h2      = (float*)(ws + 163840000);      //   6,720,000
  float* a_s1    = (float*)(ws + 170560000);      //   1,280,000
  float* a_d1    = (float*)(ws + 171840000);      //   1,280,000
  float* a_s2    = (float*)(ws + 173120000);      //     160,000
  float* a_d2    = (float*)(ws + 173280000);      //     160,000
  int*   deg     = (int*)  (ws + 173440000);      //     160,000
  int*   start   = (int*)  (ws + 173600000);      //     160,000
  int*   cur     = (int*)  (ws + 173760000);      //     160,000
  int*   tmp     = (int*)  (ws + 173920000);      //     160,000
  int*   csr_src = (int*)  (ws + 174080000);      //     800,000
  int*   csr_dst = (int*)  (ws + 174880000);      //     800,000
  int*   bsum    = (int*)  (ws + 175680000);      //       1,024
  u16*   w1t     = (u16*)  (ws + 175681024);      //   2,490,368
  u16*   w2t     = (u16*)  (ws + 178171392);      //     262,144
  float* as1c    = (float*)(ws + 178433536);      //       8,192
  float* ad1c    = (float*)(ws + 178441728);      //       8,192
  float* b1c     = (float*)(ws + 178449920);      //       8,192
  float* as2c    = (float*)(ws + 178458112);      //         256
  float* ad2c    = (float*)(ws + 178458368);      //         256
  float* b2c     = (float*)(ws + 178458624);      //         256
  int*   flags   = (int*)  (ws + 178458880);      //         256
  const size_t TOTAL_BASE = 178459136;
  u16*   xb      = (u16*)  (ws + TOTAL_BASE);     //  48,873,472 (path A only)
  const size_t TOTAL_A = TOTAL_BASE + (size_t)MP * KP * 2;  // 227,332,608 (< proven 233.6MB)
  if (ws_size < TOTAL_BASE) return;
  const bool pathA = (ws_size >= TOTAL_A);

  probe_k<<<1, 64, 0, stream>>>((const u32*)x, ei, flags);

  cvt_f32_k<<<(F1 + 255) / 256, 256, 0, stream>>>(as1, as1c, F1, flags);
  cvt_f32_k<<<(F1 + 255) / 256, 256, 0, stream>>>(ad1, ad1c, F1, flags);
  cvt_f32_k<<<(F1 + 255) / 256, 256, 0, stream>>>(b1, b1c, F1, flags);
  cvt_f32_k<<<1, 256, 0, stream>>>(as2, as2c, C2, flags);
  cvt_f32_k<<<1, 256, 0, stream>>>(ad2, ad2c, C2, flags);
  cvt_f32_k<<<1, 256, 0, stream>>>(b2, b2c, C2, flags);
  w1t_k<<<dim3(8, KP), 256, 0, stream>>>(W1, w1t, flags);
  w2t_k<<<(64 * F1 + 255) / 256, 256, 0, stream>>>(W2, w2t, flags);

  hipMemsetAsync(deg, 0, NN * sizeof(int), stream);
  hipMemsetAsync(a_s1, 0, 2 * NN * NH1 * sizeof(float), stream);  // a_s1 + a_d1 contiguous
  const int EB = (ETOT + 255) / 256;
  deg_k  <<<EB, 256, 0, stream>>>(ei, deg, flags);
  scan1_k<<<NB, 256, 0, stream>>>(deg, tmp, bsum);
  scan2_k<<<1, 256, 0, stream>>>(bsum);
  scan3_k<<<NB, 256, 0, stream>>>(deg, tmp, bsum, start, cur);
  fill_k <<<EB, 256, 0, stream>>>(ei, cur, csr_src, csr_dst, flags);

  if (pathA) {
    xb_k<<<dim3((KP + 255) / 256, MP), 256, 0, stream>>>(x, xb, flags);
    gemm1c_k<<<dim3(8, MP / 256), 512, 0, stream>>>(xb, w1t, h1, as1c, ad1c, a_s1, a_d1);
  } else {
    gemm1m_k<<<dim3(16, 313), 256, 0, stream>>>(x, w1t, h1, flags);
    att1_k<<<NN, 256, 0, stream>>>(h1, as1c, ad1c, a_s1, a_d1);
  }
  gfuse_k<<<NN / 16, 512, 0, stream>>>(start, deg, csr_src, a_s1, a_d1, h1, b1c, w2t, h2);

  att2_k<<<NN, 64, 0, stream>>>(h2, as2c, ad2c, a_s2, a_d2);
  gath2_k<<<NN, 64, 0, stream>>>(start, deg, csr_src, a_s2, a_d2, h2, b2c, d_out, flags);
}